// Round 7
// baseline (229.301 us; speedup 1.0000x reference)
//
#include <hip/hip_runtime.h>
#include <hip/hip_cooperative_groups.h>
#include <math.h>

namespace cgn = cooperative_groups;

// GenModel_81381040325247 — cooperative single-kernel parallel-in-time.
// Phase A: blocks 0-7 {LDS-LUT build + RK4(16) z_init}; blocks 8-511 segment
//          dW sums (BW-bound, hides A's latency work).      grid.sync()
// Phase B: blocks 0-7 Euler coarse chain (z in regs, LDS LUT); blocks 8-511
//          build their LDS LUT (hides under the chain).     grid.sync()
// Phase C: all threads fine-sweep M*4096 segment chains (1-2 chains/thread).
// Kills R6's ~50us of fixed overhead: dispatch gaps, fill kernel, global LUT
// staging x3, and the half-idle fine grid when ws forces M=32.
// Fallback: R6's proven 4-kernel path if cooperative launch errors.

#define NPART  4096
#define NROWS  4096
#define NSTEPS 4095
#define NH     24
#define TG     70
#define TCELLS (TG * TG)          // 4900
#define ZSCALE 5.75f              // (TG-1)/12
#define OFS    34.5f              // -(-6)*ZSCALE
#define HI     68.999f
#define DTS    (1.0f / 4095.0f)

__device__ __forceinline__ float exp2_hw(float x) {
  float r;
  asm("v_exp_f32 %0, %1" : "=v"(r) : "v"(x));
  return r;
}
__device__ __forceinline__ float tanh_hw(float x) {
  float e = exp2_hw(x * 2.8853900817779268f);   // e^{2x}
  float r = __builtin_amdgcn_rcpf(1.0f + e);
  return fmaf(-2.0f, r, 1.0f);
}

// exact MLP eval at grid node idx (fast transcendentals; ~1e-6 vs libm)
__device__ __forceinline__ void mlp_eval_fast(int idx,
    const float* __restrict__ Wf1, const float* __restrict__ bf1,
    const float* __restrict__ Wf2, const float* __restrict__ bf2,
    const float* __restrict__ Wg1, const float* __restrict__ bg1,
    const float* __restrict__ Wg2, const float* __restrict__ bg2,
    float& f0, float& f1, float& cgv)
{
  int iy = idx / TG, ix = idx - iy * TG;
  float z0 = -6.0f + ix * (12.0f / (TG - 1));
  float z1 = -6.0f + iy * (12.0f / (TG - 1));
  f0 = bf2[0]; f1 = bf2[1];
  #pragma unroll 4
  for (int h = 0; h < NH; ++h) {
    float t = tanh_hw(fmaf(z0, Wf1[h], fmaf(z1, Wf1[NH + h], bf1[h])));
    f0 = fmaf(t, Wf2[2 * h], f0);
    f1 = fmaf(t, Wf2[2 * h + 1], f1);
  }
  float gp = bg2[0];
  #pragma unroll 4
  for (int h = 0; h < NH; ++h) {
    float t = tanh_hw(fmaf(z0, Wg1[h], fmaf(z1, Wg1[NH + h], bg1[h])));
    gp = fmaf(t, Wg2[h], gp);
  }
  float sg = __builtin_amdgcn_rcpf(1.0f + exp2_hw(-gp * 1.4426950408889634f));
  cgv = 0.3f * sg * sqrtf(DTS);
}

__device__ __forceinline__ void lut_eval(const float4* __restrict__ tabs,
                                         float zx, float zy,
                                         float& F0, float& F1, float& CGv)
{
  float x = fminf(fmaxf(fmaf(zx, ZSCALE, OFS), 0.0f), HI);
  float y = fminf(fmaxf(fmaf(zy, ZSCALE, OFS), 0.0f), HI);
  float fxi = floorf(x), fyi = floorf(y);
  float fx = x - fxi, fy = y - fyi;
  int b = (int)fyi * TG + (int)fxi;
  float4 c00 = tabs[b], c10 = tabs[b + 1], c01 = tabs[b + TG], c11 = tabs[b + TG + 1];
  float u0 = fmaf(fx, c10.x - c00.x, c00.x), u1 = fmaf(fx, c11.x - c01.x, c01.x);
  F0 = fmaf(fy, u1 - u0, u0);
  u0 = fmaf(fx, c10.y - c00.y, c00.y); u1 = fmaf(fx, c11.y - c01.y, c01.y);
  F1 = fmaf(fy, u1 - u0, u0);
  u0 = fmaf(fx, c10.z - c00.z, c00.z); u1 = fmaf(fx, c11.z - c01.z, c01.z);
  CGv = fmaf(fy, u1 - u0, u0);
}

// ================= cooperative mega-kernel =================
__global__ void __launch_bounds__(512, 4)
mega_kernel(const float* __restrict__ Wf1, const float* __restrict__ bf1,
            const float* __restrict__ Wf2, const float* __restrict__ bf2,
            const float* __restrict__ Wg1, const float* __restrict__ bg1,
            const float* __restrict__ Wg2, const float* __restrict__ bg2,
            const float* __restrict__ term_loc, const float* __restrict__ lts,
            const float* __restrict__ eps, const float* __restrict__ dW,
            float* __restrict__ SdW, float* __restrict__ Z0,
            float* __restrict__ out, int M)
{
  __shared__ float4 tabs[TCELLS];                 // 78400 B -> 2 blocks/CU
  const int bid = blockIdx.x, tix = threadIdx.x;
  const int tid = bid * 512 + tix;
  const int m = NROWS / M;
  float2 zreg = make_float2(0.0f, 0.0f);

  float* zinit = out;
  float* zforw = out + 2 * NPART;
  float* zsamp = out + 2 * NPART + 2 * (size_t)NPART * NROWS;

  // ---------------- phase A ----------------
  if (bid < 8) {
    for (int idx = tix; idx < TCELLS; idx += 512) {
      float f0, f1, cgv;
      mlp_eval_fast(idx, Wf1, bf1, Wf2, bf2, Wg1, bg1, Wg2, bg2, f0, f1, cgv);
      tabs[idx] = make_float4(f0, f1, cgv, 0.0f);
    }
    __syncthreads();
    // RK4(16) for particle p = tid (0..4095)
    const int p = tid;
    const int q = p & 3;
    const float stdv = expf(lts[q]);
    float z0 = fmaf(stdv, eps[2 * p],     term_loc[2 * q]);
    float z1 = fmaf(stdv, eps[2 * p + 1], term_loc[2 * q + 1]);
    const float dt = 1.0f / 16.0f;
    #pragma unroll 1
    for (int st = 0; st < 16; ++st) {
      float K10, K11, K20, K21, K30, K31, K40, K41, cgd;
      lut_eval(tabs, z0, z1, K10, K11, cgd);
      lut_eval(tabs, fmaf(-0.5f * dt, K10, z0), fmaf(-0.5f * dt, K11, z1), K20, K21, cgd);
      lut_eval(tabs, fmaf(-0.5f * dt, K20, z0), fmaf(-0.5f * dt, K21, z1), K30, K31, cgd);
      lut_eval(tabs, fmaf(-dt, K30, z0), fmaf(-dt, K31, z1), K40, K41, cgd);
      z0 -= dt * (1.0f / 6.0f) * (K10 + 2.0f * (K20 + K30) + K40);
      z1 -= dt * (1.0f / 6.0f) * (K11 + 2.0f * (K21 + K31) + K41);
    }
    *(float2*)(zinit + 2 * p) = make_float2(z0, z1);
    *(float2*)(zforw + 2 * p) = make_float2(z0, z1);    // row 0
    if (p == 0) *(float2*)zsamp = make_float2(z0, z1);  // diag t=0
    *(float2*)(Z0 + 2 * p) = make_float2(z0, z1);
    zreg = make_float2(z0, z1);
  } else {
    // segment dW sums: pairs (s, v), v = float4 column 0..2047
    const int P = M * 2048;
    const int pi = tid - 4096;                    // 0..258047
    #pragma unroll 1
    for (int rep = 0; rep < 2; ++rep) {
      int pp = pi + rep * 258048;
      if (pp < P) {
        int s = pp >> 11, v = pp & 2047;
        int t0 = s * m, t1 = min(t0 + m, NSTEPS);
        const float4* qq = (const float4*)dW + (size_t)t0 * 2048 + v;
        float4 a = make_float4(0.f, 0.f, 0.f, 0.f);
        float4 c = make_float4(0.f, 0.f, 0.f, 0.f);
        int t = t0;
        for (; t + 1 < t1; t += 2) {
          float4 w0 = qq[0];
          float4 w1 = qq[2048];
          a.x += w0.x; a.y += w0.y; a.z += w0.z; a.w += w0.w;
          c.x += w1.x; c.y += w1.y; c.z += w1.z; c.w += w1.w;
          qq += 4096;
        }
        if (t < t1) { float4 w0 = qq[0]; a.x += w0.x; a.y += w0.y; a.z += w0.z; a.w += w0.w; }
        a.x += c.x; a.y += c.y; a.z += c.z; a.w += c.w;
        ((float4*)SdW)[(size_t)s * 2048 + v] = a;
      }
    }
  }
  cgn::this_grid().sync();

  // ---------------- phase B ----------------
  if (bid < 8) {
    // Euler coarse chain from registers
    const int p = tid;
    const float segdt = (float)m * DTS;
    float2 z = zreg;
    float2 S = *(const float2*)(SdW + 2 * p);
    #pragma unroll 1
    for (int s = 0; s < M - 1; ++s) {
      float2 Sn = S;
      if (s + 2 < M) Sn = *(const float2*)(SdW + (size_t)(s + 1) * 8192 + 2 * p);
      float F0, F1, CGv;
      lut_eval(tabs, z.x, z.y, F0, F1, CGv);
      z.x = fmaf(CGv, S.x, fmaf(F0, segdt, z.x));
      z.y = fmaf(CGv, S.y, fmaf(F1, segdt, z.y));
      *(float2*)(Z0 + (size_t)(s + 1) * 8192 + 2 * p) = z;
      S = Sn;
    }
  } else {
    // build this block's LUT while the chain runs
    for (int idx = tix; idx < TCELLS; idx += 512) {
      float f0, f1, cgv;
      mlp_eval_fast(idx, Wf1, bf1, Wf2, bf2, Wg1, bg1, Wg2, bg2, f0, f1, cgv);
      tabs[idx] = make_float4(f0, f1, cgv, 0.0f);
    }
    __syncthreads();
  }
  cgn::this_grid().sync();

  // ---------------- phase C: fine sweep ----------------
  {
    const int CT = M * NPART;
    int c0 = tid, c1 = tid + 262144;
    bool A0 = c0 < CT, A1 = c1 < CT;
    if (A0 || A1) {
      int s0 = c0 >> 12, p0 = c0 & 4095;
      int s1 = c1 >> 12, p1 = c1 & 4095;
      int t00 = s0 * m, t01 = s1 * m;
      int n0 = A0 ? min(m, NSTEPS - t00) : 0;
      int n1 = A1 ? min(m, NSTEPS - t01) : 0;
      float2 za = make_float2(0.f, 0.f), zb = make_float2(0.f, 0.f);
      if (A0) za = *(const float2*)(Z0 + (size_t)s0 * 8192 + 2 * p0);
      if (A1) zb = *(const float2*)(Z0 + (size_t)s1 * 8192 + 2 * p1);
      const float2* dpa = (const float2*)dW + (size_t)t00 * NPART + p0;
      const float2* dpb = (const float2*)dW + (size_t)t01 * NPART + p1;
      float* ra = zforw + ((size_t)(t00 + 1) * NPART + p0) * 2;
      float* rb = zforw + ((size_t)(t01 + 1) * NPART + p1) * 2;
      float2 dca = make_float2(0.f, 0.f), dcb = make_float2(0.f, 0.f);
      if (n0 > 0) dca = *dpa;
      if (n1 > 0) dcb = *dpb;
      #pragma unroll 1
      for (int k = 0; k < m; ++k) {
        float2 dna = dca, dnb = dcb;
        if (k + 1 < n0) dna = dpa[NPART];
        if (k + 1 < n1) dnb = dpb[NPART];
        if (k < n0) {
          float F0, F1, CGv;
          lut_eval(tabs, za.x, za.y, F0, F1, CGv);
          za.x = fmaf(CGv, dca.x, fmaf(F0, DTS, za.x));
          za.y = fmaf(CGv, dca.y, fmaf(F1, DTS, za.y));
          union { float2 f; double d; } u; u.f = za;
          __builtin_nontemporal_store(u.d, (double*)ra);
          if (t00 + k + 1 == p0) *(float2*)(zsamp + 2 * p0) = za;
        }
        if (k < n1) {
          float F0, F1, CGv;
          lut_eval(tabs, zb.x, zb.y, F0, F1, CGv);
          zb.x = fmaf(CGv, dcb.x, fmaf(F0, DTS, zb.x));
          zb.y = fmaf(CGv, dcb.y, fmaf(F1, DTS, zb.y));
          union { float2 f; double d; } u; u.f = zb;
          __builtin_nontemporal_store(u.d, (double*)rb);
          if (t01 + k + 1 == p1) *(float2*)(zsamp + 2 * p1) = zb;
        }
        ra += 2 * NPART; rb += 2 * NPART;
        dca = dna; dcb = dnb;
        dpa += NPART; dpb += NPART;
      }
    }
  }
}

// ================= fallback path (R6, proven) =================
__device__ __forceinline__ void mlp_eval(int idx,
    const float* Wf1, const float* bf1, const float* Wf2, const float* bf2,
    const float* Wg1, const float* bg1, const float* Wg2, const float* bg2,
    float& f0, float& f1, float& cg)
{
  int iy = idx / TG, ix = idx - iy * TG;
  float z0 = -6.0f + ix * (12.0f / (TG - 1));
  float z1 = -6.0f + iy * (12.0f / (TG - 1));
  f0 = bf2[0]; f1 = bf2[1];
  for (int h = 0; h < NH; ++h) {
    float t = tanhf(fmaf(z0, Wf1[h], fmaf(z1, Wf1[NH + h], bf1[h])));
    f0 = fmaf(t, Wf2[2 * h], f0);
    f1 = fmaf(t, Wf2[2 * h + 1], f1);
  }
  float gp = bg2[0];
  for (int h = 0; h < NH; ++h) {
    float t = tanhf(fmaf(z0, Wg1[h], fmaf(z1, Wg1[NH + h], bg1[h])));
    gp = fmaf(t, Wg2[h], gp);
  }
  cg = 0.3f / (1.0f + expf(-gp)) * sqrtf(DTS);
}

__global__ void fill_packed(const float* __restrict__ Wf1, const float* __restrict__ bf1,
                            const float* __restrict__ Wf2, const float* __restrict__ bf2,
                            const float* __restrict__ Wg1, const float* __restrict__ bg1,
                            const float* __restrict__ Wg2, const float* __restrict__ bg2,
                            float4* __restrict__ tab4)
{
  int idx = blockIdx.x * blockDim.x + threadIdx.x;
  if (idx >= TCELLS) return;
  float f0, f1, cg;
  mlp_eval(idx, Wf1, bf1, Wf2, bf2, Wg1, bg1, Wg2, bg2, f0, f1, cg);
  tab4[idx] = make_float4(f0, f1, cg, 0.0f);
}

__global__ void __launch_bounds__(256)
sumrk4_kernel(const float* __restrict__ dW, float* __restrict__ SdW,
              const float4* __restrict__ tab4,
              const float* __restrict__ term_loc, const float* __restrict__ lts,
              const float* __restrict__ eps,
              float* __restrict__ Z0, float* __restrict__ out, int M)
{
  const int bid = blockIdx.x;
  if (bid >= 16) {
    const int b  = bid - 16;
    const int m  = NROWS / M;
    const int s  = b >> 3;
    const int v  = ((b & 7) << 8) + threadIdx.x;
    const int t0 = s * m;
    const int t1 = min(t0 + m, NSTEPS);
    const float4* q = (const float4*)dW + (size_t)t0 * 2048 + v;
    float4 a = make_float4(0.f, 0.f, 0.f, 0.f);
    float4 c = make_float4(0.f, 0.f, 0.f, 0.f);
    int t = t0;
    for (; t + 1 < t1; t += 2) {
      float4 w0 = q[0];
      float4 w1 = q[2048];
      a.x += w0.x; a.y += w0.y; a.z += w0.z; a.w += w0.w;
      c.x += w1.x; c.y += w1.y; c.z += w1.z; c.w += w1.w;
      q += 4096;
    }
    if (t < t1) { float4 w0 = q[0]; a.x += w0.x; a.y += w0.y; a.z += w0.z; a.w += w0.w; }
    a.x += c.x; a.y += c.y; a.z += c.z; a.w += c.w;
    ((float4*)SdW)[(size_t)s * 2048 + v] = a;
    return;
  }
  const int p = bid * 256 + threadIdx.x;
  const int q = p & 3;
  const float stdv = expf(lts[q]);
  float z0 = fmaf(stdv, eps[2 * p],     term_loc[2 * q]);
  float z1 = fmaf(stdv, eps[2 * p + 1], term_loc[2 * q + 1]);
  auto evalF = [&](float y0, float y1, float& F0, float& F1) {
    float x = fminf(fmaxf(fmaf(y0, ZSCALE, OFS), 0.0f), HI);
    float y = fminf(fmaxf(fmaf(y1, ZSCALE, OFS), 0.0f), HI);
    float fxi = floorf(x), fyi = floorf(y);
    float fx = x - fxi, fy = y - fyi;
    int b = (int)fyi * TG + (int)fxi;
    float4 c00 = tab4[b], c10 = tab4[b + 1], c01 = tab4[b + TG], c11 = tab4[b + TG + 1];
    float u0 = fmaf(fx, c10.x - c00.x, c00.x), u1 = fmaf(fx, c11.x - c01.x, c01.x);
    F0 = fmaf(fy, u1 - u0, u0);
    u0 = fmaf(fx, c10.y - c00.y, c00.y); u1 = fmaf(fx, c11.y - c01.y, c01.y);
    F1 = fmaf(fy, u1 - u0, u0);
  };
  const float dt = 1.0f / 16.0f;
  #pragma unroll 1
  for (int st = 0; st < 16; ++st) {
    float K10, K11, K20, K21, K30, K31, K40, K41;
    evalF(z0, z1, K10, K11);
    evalF(fmaf(-0.5f * dt, K10, z0), fmaf(-0.5f * dt, K11, z1), K20, K21);
    evalF(fmaf(-0.5f * dt, K20, z0), fmaf(-0.5f * dt, K21, z1), K30, K31);
    evalF(fmaf(-dt, K30, z0), fmaf(-dt, K31, z1), K40, K41);
    z0 -= dt * (1.0f / 6.0f) * (K10 + 2.0f * (K20 + K30) + K40);
    z1 -= dt * (1.0f / 6.0f) * (K11 + 2.0f * (K21 + K31) + K41);
  }
  float* zforw = out + 2 * NPART;
  float* zsamp = out + 2 * NPART + 2 * (size_t)NPART * NROWS;
  *(float2*)(out + 2 * p) = make_float2(z0, z1);
  *(float2*)(zforw + 2 * p) = make_float2(z0, z1);
  if (p == 0) *(float2*)zsamp = make_float2(z0, z1);
  *(float2*)(Z0 + 2 * p) = make_float2(z0, z1);
}

__global__ void __launch_bounds__(256, 1)
chain_kernel(const float4* __restrict__ tab4, const float* __restrict__ SdW,
             float* __restrict__ Z0, int M)
{
  __shared__ float4 tabs[TCELLS];
  for (int i = threadIdx.x; i < TCELLS; i += 256) tabs[i] = tab4[i];
  __syncthreads();
  const int p = blockIdx.x * 256 + threadIdx.x;
  float2 z = *(const float2*)(Z0 + 2 * p);
  const float segdt = (float)(NROWS / M) * DTS;
  float2 S  = *(const float2*)(SdW + 2 * p);
  float2 Sn;
  #pragma unroll 1
  for (int s = 0; s < M - 1; ++s) {
    if (s + 2 < M) Sn = *(const float2*)(SdW + (size_t)(s + 1) * (2 * NPART) + 2 * p);
    float F0, F1, CGv;
    lut_eval(tabs, z.x, z.y, F0, F1, CGv);
    z.x = fmaf(CGv, S.x, fmaf(F0, segdt, z.x));
    z.y = fmaf(CGv, S.y, fmaf(F1, segdt, z.y));
    *(float2*)(Z0 + (size_t)(s + 1) * (2 * NPART) + 2 * p) = z;
    S = Sn;
  }
}

__global__ void __launch_bounds__(1024, 4)
fine_kernel(const float4* __restrict__ tab4, const float* __restrict__ dW,
            const float* __restrict__ Z0, float* __restrict__ out, int M)
{
  const int m = NROWS / M;
  const int s = blockIdx.x >> 2;
  const int p = ((blockIdx.x & 3) << 10) + threadIdx.x;
  __shared__ float4 tabs[TCELLS];
  for (int i = threadIdx.x; i < TCELLS; i += 1024) tabs[i] = tab4[i];
  __syncthreads();
  const int t0  = s * m;
  const int nst = min(m, NSTEPS - t0);
  float2 z = *(const float2*)(Z0 + (size_t)s * (2 * NPART) + 2 * p);
  const float2* dwp = (const float2*)dW + (size_t)t0 * NPART + p;
  float* rowp  = out + 2 * NPART + ((size_t)(t0 + 1) * NPART + p) * 2;
  float* zsamp = out + 2 * NPART + 2 * (size_t)NPART * NROWS;
  float2 dwc = *dwp;
  #pragma unroll 1
  for (int k = 0; k < nst; ++k) {
    float2 dwn = dwc;
    if (k + 1 < nst) dwn = dwp[NPART];
    float F0, F1, CGv;
    lut_eval(tabs, z.x, z.y, F0, F1, CGv);
    z.x = fmaf(CGv, dwc.x, fmaf(F0, DTS, z.x));
    z.y = fmaf(CGv, dwc.y, fmaf(F1, DTS, z.y));
    union { float2 f; double d; } u; u.f = z;
    __builtin_nontemporal_store(u.d, (double*)rowp);
    if (t0 + k + 1 == p) *(float2*)(zsamp + 2 * p) = z;
    rowp += 2 * NPART;
    dwc = dwn;
    dwp += NPART;
  }
}

// ---------------- host ----------------
extern "C" void kernel_launch(void* const* d_in, const int* in_sizes, int n_in,
                              void* d_out, int out_size, void* d_ws, size_t ws_size,
                              hipStream_t stream) {
  // inputs: [0]=N [1]=Wf1 [2]=bf1 [3]=Wf2 [4]=bf2 [5]=Wg1 [6]=bg1 [7]=Wg2
  //         [8]=bg2 [9]=term_loc [10]=log_term_std [11]=noise_eps [12]=dW
  const float* Wf1 = (const float*)d_in[1];
  const float* bf1 = (const float*)d_in[2];
  const float* Wf2 = (const float*)d_in[3];
  const float* bf2 = (const float*)d_in[4];
  const float* Wg1 = (const float*)d_in[5];
  const float* bg1 = (const float*)d_in[6];
  const float* Wg2 = (const float*)d_in[7];
  const float* bg2 = (const float*)d_in[8];
  const float* tl  = (const float*)d_in[9];
  const float* lts = (const float*)d_in[10];
  const float* eps = (const float*)d_in[11];
  const float* dW  = (const float*)d_in[12];
  float* outp = (float*)d_out;

  // ---- cooperative path: ws = SdW[M][8192] + Z0[M][8192] ----
  int M = 0;
  if      (ws_size >= 2ull * 128 * 8192 * 4) M = 128;
  else if (ws_size >= 2ull *  64 * 8192 * 4) M = 64;
  else if (ws_size >= 2ull *  32 * 8192 * 4) M = 32;

  bool done = false;
  if (M) {
    float* SdW = (float*)d_ws;
    float* Z0  = SdW + (size_t)M * 8192;
    void* args[] = { (void*)&Wf1, (void*)&bf1, (void*)&Wf2, (void*)&bf2,
                     (void*)&Wg1, (void*)&bg1, (void*)&Wg2, (void*)&bg2,
                     (void*)&tl,  (void*)&lts, (void*)&eps, (void*)&dW,
                     (void*)&SdW, (void*)&Z0,  (void*)&outp, (void*)&M };
    hipError_t e = hipLaunchCooperativeKernel((const void*)mega_kernel,
                                              dim3(512), dim3(512),
                                              args, 0, stream);
    done = (e == hipSuccess);
  }

  if (!done) {
    // ---- fallback: R6 multi-kernel path ----
    const size_t tabBA = 78848;
    auto need = [&](size_t MM) { return tabBA + 2ull * MM * 8192ull * 4ull; };
    if (ws_size >= need(32)) {
      const int MF = (ws_size >= need(128)) ? 128 : ((ws_size >= need(64)) ? 64 : 32);
      char* ws = (char*)d_ws;
      float4* tab4 = (float4*)ws;
      float*  SdW  = (float*)(ws + tabBA);
      float*  Z0   = SdW + (size_t)MF * 8192;
      fill_packed<<<dim3(20), dim3(256), 0, stream>>>(Wf1, bf1, Wf2, bf2,
                                                      Wg1, bg1, Wg2, bg2, tab4);
      sumrk4_kernel<<<dim3(16 + MF * 8), dim3(256), 0, stream>>>(
          dW, SdW, tab4, tl, lts, eps, Z0, outp, MF);
      chain_kernel<<<dim3(16), dim3(256), 0, stream>>>(tab4, SdW, Z0, MF);
      fine_kernel<<<dim3(MF * 4), dim3(1024), 0, stream>>>(tab4, dW, Z0, outp, MF);
    }
    // (ws too small for any path is not expected; outputs would be invalid)
  }
}